// Round 1
// baseline (508.782 us; speedup 1.0000x reference)
//
#include <hip/hip_runtime.h>
#include <stdint.h>

typedef unsigned short ushort_t;

#define KK3 3
#define IC 32      // input capsules
#define IP 16      // input pose
#define OC 32      // output capsules
#define OP 16      // output pose
#define NI 288     // KK3*KK3*IC (im2col "i" dimension)
#define HH 12
#define WWW 12
#define NTOT 1152  // b*h*w
#define CQ 512     // OC*OP
#define EPSQ 1e-9f

__device__ __forceinline__ float bf_lo(unsigned u) { return __uint_as_float(u << 16); }
__device__ __forceinline__ float bf_hi(unsigned u) { return __uint_as_float(u & 0xffff0000u); }
__device__ __forceinline__ ushort_t f2bf(float f) {
    unsigned u = __float_as_uint(f);
    return (ushort_t)((u + 0x7fffu + ((u >> 16) & 1u)) >> 16);   // RNE
}

// ---------------------------------------------------------------------------
// Kernel A: votes[nl][i][c][q] (bf16) for one pixel chunk.
// grid = (NI, ceil(cnt/64)), block = 128.  thread t -> (c = t>>2, qq = t&3)
// each thread holds W[i, c, :, qq*4..qq*4+4) in 16 float4 regs, loops 64 pixels.
// ---------------------------------------------------------------------------
__global__ __launch_bounds__(128) void votes_kernel(
    const float* __restrict__ x, const float* __restrict__ Wg,
    ushort_t* __restrict__ votes, int nStart, int nCount)
{
    __shared__ float u_lds[64][IP];

    const int i = blockIdx.x;
    const int tileBase = blockIdx.y * 64;
    const int nC = min(64, nCount - tileBase);
    const int t = threadIdx.x;
    const int c = t >> 2;
    const int qq = t & 3;

    const int ky = i / (KK3 * IC);
    const int kx = (i / IC) % KK3;
    const int ic = i % IC;

    // stage u[n-tile, i, :] (im2col gather with SAME zero padding)
    {
        const int nl = t >> 1;
        const int ph = (t & 1) * 8;
        if (nl < nC) {
            const int n = nStart + tileBase + nl;
            const int b = n / (HH * WWW);
            const int rem = n % (HH * WWW);
            const int y = rem / WWW;
            const int xx = rem % WWW;
            const int sy = y + ky - 1;
            const int sx = xx + kx - 1;
            float4 v0 = make_float4(0.f, 0.f, 0.f, 0.f), v1 = v0;
            if (sy >= 0 && sy < HH && sx >= 0 && sx < WWW) {
                const float* src = x + ((((size_t)b * HH + sy) * WWW + sx) * IC + ic) * IP + ph;
                v0 = *(const float4*)(src);
                v1 = *(const float4*)(src + 4);
            }
            *(float4*)&u_lds[nl][ph] = v0;
            *(float4*)&u_lds[nl][ph + 4] = v1;
        }
    }

    // W[i, c, p, qq*4 .. +4) -> regs
    float4 w[IP];
    {
        const float* wb = Wg + ((size_t)i * OC + c) * (IP * OP) + qq * 4;
#pragma unroll
        for (int p = 0; p < IP; ++p) w[p] = *(const float4*)(wb + p * OP);
    }
    __syncthreads();

    ushort_t* vb = votes + ((size_t)tileBase * NI + i) * CQ + c * OP + qq * 4;
    for (int nl = 0; nl < nC; ++nl) {
        const float4 u0 = *(const float4*)&u_lds[nl][0];
        const float4 u1 = *(const float4*)&u_lds[nl][4];
        const float4 u2 = *(const float4*)&u_lds[nl][8];
        const float4 u3 = *(const float4*)&u_lds[nl][12];
        float a0 = 0.f, a1 = 0.f, a2 = 0.f, a3 = 0.f;
#define ACC(uf, pp)                                         \
        a0 = fmaf(uf, w[pp].x, a0); a1 = fmaf(uf, w[pp].y, a1); \
        a2 = fmaf(uf, w[pp].z, a2); a3 = fmaf(uf, w[pp].w, a3);
        ACC(u0.x, 0)  ACC(u0.y, 1)  ACC(u0.z, 2)  ACC(u0.w, 3)
        ACC(u1.x, 4)  ACC(u1.y, 5)  ACC(u1.z, 6)  ACC(u1.w, 7)
        ACC(u2.x, 8)  ACC(u2.y, 9)  ACC(u2.z, 10) ACC(u2.w, 11)
        ACC(u3.x, 12) ACC(u3.y, 13) ACC(u3.z, 14) ACC(u3.w, 15)
#undef ACC
        ushort4 st;
        st.x = f2bf(a0); st.y = f2bf(a1); st.z = f2bf(a2); st.w = f2bf(a3);
        *(ushort4*)vb = st;
        vb += (size_t)NI * CQ;
    }
}

// ---------------------------------------------------------------------------
// Kernel B: full DR routing for one pixel. block = 256 (4 waves), grid = cnt.
// lane l -> (c = l>>1, qh = l&1): owns votes[i, c, qh*8..+8).
// ---------------------------------------------------------------------------
__device__ __forceinline__ void reduce_squash(
    float (*sPart)[CQ], float* s_sh, float* fac_sh, float* v_sh,
    const float* __restrict__ bias, int t, float scale)
{
    __syncthreads();
#pragma unroll
    for (int r = 0; r < 2; ++r) {
        const int k = t + r * 256;
        float s = (sPart[0][k] + sPart[1][k]) + (sPart[2][k] + sPart[3][k]);
        s = fmaf(s, scale, bias[k]);
        s_sh[k] = s;
    }
    __syncthreads();
    if (t < OC) {
        float sq = 0.f;
#pragma unroll
        for (int q = 0; q < OP; ++q) { const float s = s_sh[t * OP + q]; sq = fmaf(s, s, sq); }
        fac_sh[t] = (sq / (1.0f + sq)) * rsqrtf(sq + EPSQ);   // DR squash factor
    }
    __syncthreads();
#pragma unroll
    for (int r = 0; r < 2; ++r) { const int k = t + r * 256; v_sh[k] = s_sh[k] * fac_sh[k >> 4]; }
    __syncthreads();
}

template <bool FIRST>
__device__ __forceinline__ void routed_sweep(
    const ushort_t* __restrict__ votes, size_t vbase, int wv, int c, int qh,
    float (&logits)[NI][OC], const float* vr, float* sa)
{
    for (int i = wv; i < NI; i += 4) {
        const uint4 pv = *(const uint4*)(votes + vbase + (size_t)i * CQ);
        const float p0 = bf_lo(pv.x), p1 = bf_hi(pv.x);
        const float p2 = bf_lo(pv.y), p3 = bf_hi(pv.y);
        const float p4 = bf_lo(pv.z), p5 = bf_hi(pv.z);
        const float p6 = bf_lo(pv.w), p7 = bf_hi(pv.w);
        // agreement: a[c] = sum_q votes[i,c,q] * v[c,q]   (pair-reduce over qh)
        float a = p0 * vr[0];
        a = fmaf(p1, vr[1], a); a = fmaf(p2, vr[2], a); a = fmaf(p3, vr[3], a);
        a = fmaf(p4, vr[4], a); a = fmaf(p5, vr[5], a); a = fmaf(p6, vr[6], a);
        a = fmaf(p7, vr[7], a);
        a += __shfl_xor(a, 1);
        if (FIRST) {
            if (qh == 0) logits[i][c] = a;      // logits after iter0 = agreement(v0)
        } else {
            a += logits[i][c];                   // logits after iter1
        }
        // softmax over the 32 output caps (lane bits 1..5)
        float m = a;
        m = fmaxf(m, __shfl_xor(m, 2));
        m = fmaxf(m, __shfl_xor(m, 4));
        m = fmaxf(m, __shfl_xor(m, 8));
        m = fmaxf(m, __shfl_xor(m, 16));
        m = fmaxf(m, __shfl_xor(m, 32));
        const float e = __expf(a - m);
        float es = e;
        es += __shfl_xor(es, 2);
        es += __shfl_xor(es, 4);
        es += __shfl_xor(es, 8);
        es += __shfl_xor(es, 16);
        es += __shfl_xor(es, 32);
        const float coup = __fdividef(e, es);
        sa[0] = fmaf(coup, p0, sa[0]); sa[1] = fmaf(coup, p1, sa[1]);
        sa[2] = fmaf(coup, p2, sa[2]); sa[3] = fmaf(coup, p3, sa[3]);
        sa[4] = fmaf(coup, p4, sa[4]); sa[5] = fmaf(coup, p5, sa[5]);
        sa[6] = fmaf(coup, p6, sa[6]); sa[7] = fmaf(coup, p7, sa[7]);
    }
}

__global__ __launch_bounds__(256) void route_kernel(
    const ushort_t* __restrict__ votes, const float* __restrict__ bias,
    float* __restrict__ out, int nStart)
{
    __shared__ float logits[NI][OC];   // 36 KB
    __shared__ float sPart[4][CQ];     // 8 KB
    __shared__ float s_sh[CQ];
    __shared__ float v_sh[CQ];
    __shared__ float fac_sh[OC];

    const int bn = blockIdx.x;
    const int t = threadIdx.x;
    const int wv = t >> 6;
    const int l = t & 63;
    const int c = l >> 1;
    const int qh = l & 1;
    const size_t vbase = (size_t)bn * NI * CQ + c * OP + qh * 8;

    // ---- iter 0: uniform coupling -> s0 = (sum_i votes)/OC + bias
    float sa[8] = {0.f, 0.f, 0.f, 0.f, 0.f, 0.f, 0.f, 0.f};
    for (int i = wv; i < NI; i += 4) {
        const uint4 pv = *(const uint4*)(votes + vbase + (size_t)i * CQ);
        sa[0] += bf_lo(pv.x); sa[1] += bf_hi(pv.x);
        sa[2] += bf_lo(pv.y); sa[3] += bf_hi(pv.y);
        sa[4] += bf_lo(pv.z); sa[5] += bf_hi(pv.z);
        sa[6] += bf_lo(pv.w); sa[7] += bf_hi(pv.w);
    }
#pragma unroll
    for (int j = 0; j < 8; ++j) sPart[wv][c * OP + qh * 8 + j] = sa[j];
    reduce_squash(sPart, s_sh, fac_sh, v_sh, bias, t, 1.0f / OC);

    float vr[8];
#pragma unroll
    for (int j = 0; j < 8; ++j) vr[j] = v_sh[c * OP + qh * 8 + j];

    // ---- iter 1: agreement(v0) -> logits, softmax, s1
#pragma unroll
    for (int j = 0; j < 8; ++j) sa[j] = 0.f;
    routed_sweep<true>(votes, vbase, wv, c, qh, logits, vr, sa);
#pragma unroll
    for (int j = 0; j < 8; ++j) sPart[wv][c * OP + qh * 8 + j] = sa[j];
    reduce_squash(sPart, s_sh, fac_sh, v_sh, bias, t, 1.0f);

    // ---- iter 2: logits + agreement(v1), softmax, s2 -> v out
#pragma unroll
    for (int j = 0; j < 8; ++j) vr[j] = v_sh[c * OP + qh * 8 + j];
#pragma unroll
    for (int j = 0; j < 8; ++j) sa[j] = 0.f;
    routed_sweep<false>(votes, vbase, wv, c, qh, logits, vr, sa);
#pragma unroll
    for (int j = 0; j < 8; ++j) sPart[wv][c * OP + qh * 8 + j] = sa[j];
    reduce_squash(sPart, s_sh, fac_sh, v_sh, bias, t, 1.0f);

    const int n = nStart + bn;
    out[(size_t)n * CQ + t] = v_sh[t];
    out[(size_t)n * CQ + 256 + t] = v_sh[256 + t];
}

// ---------------------------------------------------------------------------
extern "C" void kernel_launch(void* const* d_in, const int* in_sizes, int n_in,
                              void* d_out, int out_size, void* d_ws, size_t ws_size,
                              hipStream_t stream)
{
    const float* x = (const float*)d_in[0];
    const float* Wg = (const float*)d_in[1];
    const float* bias = (const float*)d_in[2];
    float* out = (float*)d_out;
    ushort_t* votes = (ushort_t*)d_ws;

    const size_t perN = (size_t)NI * CQ * sizeof(ushort_t);  // 294912 B per pixel
    size_t fit = ws_size / perN;
    int chunk = (fit >= 384) ? 384 : (int)fit;   // 384-pixel chunk = 113 MB, L3-resident
    if (chunk < 1) chunk = 1;

    for (int start = 0; start < NTOT; start += chunk) {
        const int cnt = (NTOT - start < chunk) ? (NTOT - start) : chunk;
        dim3 gA(NI, (cnt + 63) / 64);
        hipLaunchKernelGGL(votes_kernel, gA, dim3(128), 0, stream, x, Wg, votes, start, cnt);
        hipLaunchKernelGGL(route_kernel, dim3(cnt), dim3(256), 0, stream, votes, bias, out, start);
    }
}

// Round 2
// 491.806 us; speedup vs baseline: 1.0345x; 1.0345x over previous
//
#include <hip/hip_runtime.h>
#include <stdint.h>

typedef unsigned short ushort_t;

#define KK3 3
#define IC 32      // input capsules
#define IP 16      // input pose
#define OC 32      // output capsules
#define OP 16      // output pose
#define NI 288     // KK3*KK3*IC (im2col "i" dimension)
#define HH 12
#define WWW 12
#define NTOT 1152  // b*h*w
#define CQ 512     // OC*OP
#define EPSQ 1e-9f
#define RWAVES 8   // waves per route block
#define RSTEPS 36  // NI / RWAVES i-steps per lane

__device__ __forceinline__ float bf_lo(unsigned u) { return __uint_as_float(u << 16); }
__device__ __forceinline__ float bf_hi(unsigned u) { return __uint_as_float(u & 0xffff0000u); }
__device__ __forceinline__ ushort_t f2bf(float f) {
    unsigned u = __float_as_uint(f);
    return (ushort_t)((u + 0x7fffu + ((u >> 16) & 1u)) >> 16);   // RNE
}

// ---------------------------------------------------------------------------
// Kernel A: votes[nl][i][c][q] (bf16) for one pixel chunk.  (unchanged)
// grid = (NI, ceil(cnt/64)), block = 128.  thread t -> (c = t>>2, qq = t&3)
// ---------------------------------------------------------------------------
__global__ __launch_bounds__(128) void votes_kernel(
    const float* __restrict__ x, const float* __restrict__ Wg,
    ushort_t* __restrict__ votes, int nStart, int nCount)
{
    __shared__ float u_lds[64][IP];

    const int i = blockIdx.x;
    const int tileBase = blockIdx.y * 64;
    const int nC = min(64, nCount - tileBase);
    const int t = threadIdx.x;
    const int c = t >> 2;
    const int qq = t & 3;

    const int ky = i / (KK3 * IC);
    const int kx = (i / IC) % KK3;
    const int ic = i % IC;

    {
        const int nl = t >> 1;
        const int ph = (t & 1) * 8;
        if (nl < nC) {
            const int n = nStart + tileBase + nl;
            const int b = n / (HH * WWW);
            const int rem = n % (HH * WWW);
            const int y = rem / WWW;
            const int xx = rem % WWW;
            const int sy = y + ky - 1;
            const int sx = xx + kx - 1;
            float4 v0 = make_float4(0.f, 0.f, 0.f, 0.f), v1 = v0;
            if (sy >= 0 && sy < HH && sx >= 0 && sx < WWW) {
                const float* src = x + ((((size_t)b * HH + sy) * WWW + sx) * IC + ic) * IP + ph;
                v0 = *(const float4*)(src);
                v1 = *(const float4*)(src + 4);
            }
            *(float4*)&u_lds[nl][ph] = v0;
            *(float4*)&u_lds[nl][ph + 4] = v1;
        }
    }

    float4 w[IP];
    {
        const float* wb = Wg + ((size_t)i * OC + c) * (IP * OP) + qq * 4;
#pragma unroll
        for (int p = 0; p < IP; ++p) w[p] = *(const float4*)(wb + p * OP);
    }
    __syncthreads();

    ushort_t* vb = votes + ((size_t)tileBase * NI + i) * CQ + c * OP + qq * 4;
    for (int nl = 0; nl < nC; ++nl) {
        const float4 u0 = *(const float4*)&u_lds[nl][0];
        const float4 u1 = *(const float4*)&u_lds[nl][4];
        const float4 u2 = *(const float4*)&u_lds[nl][8];
        const float4 u3 = *(const float4*)&u_lds[nl][12];
        float a0 = 0.f, a1 = 0.f, a2 = 0.f, a3 = 0.f;
#define ACC(uf, pp)                                         \
        a0 = fmaf(uf, w[pp].x, a0); a1 = fmaf(uf, w[pp].y, a1); \
        a2 = fmaf(uf, w[pp].z, a2); a3 = fmaf(uf, w[pp].w, a3);
        ACC(u0.x, 0)  ACC(u0.y, 1)  ACC(u0.z, 2)  ACC(u0.w, 3)
        ACC(u1.x, 4)  ACC(u1.y, 5)  ACC(u1.z, 6)  ACC(u1.w, 7)
        ACC(u2.x, 8)  ACC(u2.y, 9)  ACC(u2.z, 10) ACC(u2.w, 11)
        ACC(u3.x, 12) ACC(u3.y, 13) ACC(u3.z, 14) ACC(u3.w, 15)
#undef ACC
        ushort4 st;
        st.x = f2bf(a0); st.y = f2bf(a1); st.z = f2bf(a2); st.w = f2bf(a3);
        *(ushort4*)vb = st;
        vb += (size_t)NI * CQ;
    }
}

// ---------------------------------------------------------------------------
// Kernel B: DR routing, votes register-resident across all 3 iterations.
// block = 512 (8 waves), grid = cnt pixels. lane l -> (c = l>>1, qh = l&1);
// wave wv owns i = wv + 8*r, r in [0,36). votes held as 36 x uint4 (bf16x8).
// ---------------------------------------------------------------------------
__device__ __forceinline__ void reduce_squash8(
    float (*sPart)[CQ], float* s_sh, float* fac_sh, float* v_sh,
    const float* __restrict__ bias, int t, float scale)
{
    __syncthreads();
    {
        float s = 0.f;
#pragma unroll
        for (int w = 0; w < RWAVES; ++w) s += sPart[w][t];
        s = fmaf(s, scale, bias[t]);
        s_sh[t] = s;
    }
    __syncthreads();
    if (t < OC) {
        float sq = 0.f;
#pragma unroll
        for (int q = 0; q < OP; ++q) { const float s = s_sh[t * OP + q]; sq = fmaf(s, s, sq); }
        fac_sh[t] = (sq / (1.0f + sq)) * rsqrtf(sq + EPSQ);   // DR squash factor
    }
    __syncthreads();
    v_sh[t] = s_sh[t] * fac_sh[t >> 4];
    __syncthreads();
}

#define UNPACK8(pv)                                              \
    const float p0 = bf_lo(pv.x), p1 = bf_hi(pv.x);              \
    const float p2 = bf_lo(pv.y), p3 = bf_hi(pv.y);              \
    const float p4 = bf_lo(pv.z), p5 = bf_hi(pv.z);              \
    const float p6 = bf_lo(pv.w), p7 = bf_hi(pv.w);

__global__ __launch_bounds__(512) void route_kernel(
    const ushort_t* __restrict__ votes, const float* __restrict__ bias,
    float* __restrict__ out, int nStart)
{
    __shared__ float sPart[RWAVES][CQ];   // 16 KB
    __shared__ float s_sh[CQ];
    __shared__ float v_sh[CQ];
    __shared__ float fac_sh[OC];

    const int bn = blockIdx.x;
    const int t = threadIdx.x;
    const int wv = t >> 6;
    const int l = t & 63;
    const int c = l >> 1;
    const int qh = l & 1;

    // ---- load votes into registers; accumulate iter-0 uniform sum on the fly
    uint4 pv[RSTEPS];
    float sa[8] = {0.f, 0.f, 0.f, 0.f, 0.f, 0.f, 0.f, 0.f};
    {
        const ushort_t* p = votes + (size_t)bn * NI * CQ + (size_t)wv * CQ + c * OP + qh * 8;
#pragma unroll
        for (int r = 0; r < RSTEPS; ++r) {
            pv[r] = *(const uint4*)p;
            p += (size_t)RWAVES * CQ;
        }
    }
#pragma unroll
    for (int r = 0; r < RSTEPS; ++r) {
        UNPACK8(pv[r])
        sa[0] += p0; sa[1] += p1; sa[2] += p2; sa[3] += p3;
        sa[4] += p4; sa[5] += p5; sa[6] += p6; sa[7] += p7;
    }
#pragma unroll
    for (int j = 0; j < 8; ++j) sPart[wv][c * OP + qh * 8 + j] = sa[j];
    reduce_squash8(sPart, s_sh, fac_sh, v_sh, bias, t, 1.0f / OC);

    float vr[8];
    float lg[RSTEPS];

    // ---- iters 1..2: agreement -> logits -> softmax(no max-sub) -> s
#pragma unroll
    for (int it = 1; it <= 2; ++it) {
#pragma unroll
        for (int j = 0; j < 8; ++j) vr[j] = v_sh[c * OP + qh * 8 + j];
#pragma unroll
        for (int j = 0; j < 8; ++j) sa[j] = 0.f;
#pragma unroll
        for (int r = 0; r < RSTEPS; ++r) {
            UNPACK8(pv[r])
            float a = p0 * vr[0];
            a = fmaf(p1, vr[1], a); a = fmaf(p2, vr[2], a); a = fmaf(p3, vr[3], a);
            a = fmaf(p4, vr[4], a); a = fmaf(p5, vr[5], a); a = fmaf(p6, vr[6], a);
            a = fmaf(p7, vr[7], a);
            a += __shfl_xor(a, 1);                 // pair-reduce over qh
            if (it == 1) lg[r] = a;                // logits after iter 0
            else          a += lg[r];              // accumulated logits
            // softmax over the 32 output caps (lane bits 1..5); |a| <= ~2 so
            // the max-subtraction is unnecessary (exp can't overflow)
            const float e = __expf(a);
            float es = e;
            es += __shfl_xor(es, 2);
            es += __shfl_xor(es, 4);
            es += __shfl_xor(es, 8);
            es += __shfl_xor(es, 16);
            es += __shfl_xor(es, 32);
            const float coup = __fdividef(e, es);
            sa[0] = fmaf(coup, p0, sa[0]); sa[1] = fmaf(coup, p1, sa[1]);
            sa[2] = fmaf(coup, p2, sa[2]); sa[3] = fmaf(coup, p3, sa[3]);
            sa[4] = fmaf(coup, p4, sa[4]); sa[5] = fmaf(coup, p5, sa[5]);
            sa[6] = fmaf(coup, p6, sa[6]); sa[7] = fmaf(coup, p7, sa[7]);
        }
#pragma unroll
        for (int j = 0; j < 8; ++j) sPart[wv][c * OP + qh * 8 + j] = sa[j];
        reduce_squash8(sPart, s_sh, fac_sh, v_sh, bias, t, 1.0f);
    }

    out[(size_t)(nStart + bn) * CQ + t] = v_sh[t];
}

// ---------------------------------------------------------------------------
extern "C" void kernel_launch(void* const* d_in, const int* in_sizes, int n_in,
                              void* d_out, int out_size, void* d_ws, size_t ws_size,
                              hipStream_t stream)
{
    const float* x = (const float*)d_in[0];
    const float* Wg = (const float*)d_in[1];
    const float* bias = (const float*)d_in[2];
    float* out = (float*)d_out;
    ushort_t* votes = (ushort_t*)d_ws;

    const size_t perN = (size_t)NI * CQ * sizeof(ushort_t);  // 294912 B per pixel
    size_t fit = ws_size / perN;
    int chunk = (fit >= NTOT) ? NTOT : (int)fit;
    if (chunk < 1) chunk = 1;

    for (int start = 0; start < NTOT; start += chunk) {
        const int cnt = (NTOT - start < chunk) ? (NTOT - start) : chunk;
        dim3 gA(NI, (cnt + 63) / 64);
        hipLaunchKernelGGL(votes_kernel, gA, dim3(128), 0, stream, x, Wg, votes, start, cnt);
        hipLaunchKernelGGL(route_kernel, dim3(cnt), dim3(512), 0, stream, votes, bias, out, start);
    }
}